// Round 11
// baseline (646.632 us; speedup 1.0000x reference)
//
#include <hip/hip_runtime.h>
#include <hip/hip_cooperative_groups.h>

namespace cg = cooperative_groups;

#define C_DIM 128
#define EPS 1e-5f
#define MAXNB 512        // max dst>>7 bins (n <= 65536)

typedef __attribute__((ext_vector_type(8))) short short8;
typedef __attribute__((ext_vector_type(4))) float f32x4;

__device__ __forceinline__ unsigned bf16rn(float f) {
    unsigned u = __float_as_uint(f);
    return (u + 0x7fffu + ((u >> 16) & 1u)) >> 16;
}
__device__ __forceinline__ unsigned pack_bf16(float lo, float hi) {
    return bf16rn(lo) | (bf16rn(hi) << 16);
}
__device__ __forceinline__ float blo(unsigned u) { return __uint_as_float(u << 16); }
__device__ __forceinline__ float bhi(unsigned u) { return __uint_as_float(u & 0xffff0000u); }

// ONE cooperative launch replaces the whole 8-kernel pipeline; grid.sync()
// between phases kills ~45 us of inter-launch gaps. All phases grid-agnostic.
// __launch_bounds__(256,4): <=128 regs -> 4 blocks/CU co-residency guaranteed
// (LDS ~5 KB). gemm1 uses 16-row wave tiles to stay under the reg cap.
__global__ __launch_bounds__(256, 4) void mega(
    const float* __restrict__ x,
    const int* __restrict__ esrc, const int* __restrict__ edst,
    const float* __restrict__ Wc, const float* __restrict__ bconv,
    const float* __restrict__ gamma, const float* __restrict__ beta,
    const float* __restrict__ Wfc, const float* __restrict__ bfc,
    unsigned* __restrict__ hb, unsigned* __restrict__ zb,
    unsigned short* __restrict__ WcT, unsigned short* __restrict__ WT,
    float* __restrict__ dinv, int* __restrict__ gh, int* __restrict__ binsum,
    long long* __restrict__ sorted, int* __restrict__ bsrc, int* __restrict__ rowptr,
    float* __restrict__ out, int n, int e, int nb)
{
    cg::grid_group grid = cg::this_grid();
    const int g = gridDim.x;
    const int b = blockIdx.x;
    const int t = threadIdx.x;
    const int epb = (e + g - 1) / g;
    const int w = t >> 6, lane = t & 63;
    const int wg = b * 4 + w, nw = g * 4;

    __shared__ int lds[MAXNB];
    __shared__ int ts[256];
    __shared__ int red4[4];
    __shared__ int ch[128], cbase[128], ccur[128];

    // ===== phase 1: per-block histogram of dst>>7 (LDS atomics) + weight prep =====
    {
        for (int i = t; i < nb; i += 256) lds[i] = 0;
        __syncthreads();
        int lo = b * epb, hi = min(e, lo + epb);
        for (int i = lo + t; i < hi; i += 256) atomicAdd(&lds[edst[i] >> 7], 1);
        __syncthreads();
        for (int i = t; i < nb; i += 256) gh[(long)i * g + b] = lds[i];
        if (b < 16) {
            for (int tid = b * 256 + t; tid < 128 * 128; tid += 16 * 256) {
                int nc = tid >> 7, k = tid & 127;
                WcT[tid] = (unsigned short)bf16rn(Wc[k * C_DIM + nc]);
            }
            for (int tid = b * 256 + t; tid < 48 * 128; tid += 16 * 256) {
                int nc = tid >> 7, k = tid & 127;
                float v = (nc < 40) ? Wfc[k * 40 + nc] : 0.f;
                WT[tid] = (unsigned short)bf16rn(v);
            }
        }
    }
    grid.sync();
    // ===== phase 2a: per-bin totals =====
    for (int bin = b; bin < nb; bin += g) {
        int s = 0;
        for (int i = t; i < g; i += 256) s += gh[(long)bin * g + i];
#pragma unroll
        for (int off = 1; off < 64; off <<= 1) s += __shfl_xor(s, off);
        if ((t & 63) == 0) red4[t >> 6] = s;
        __syncthreads();
        if (t == 0) binsum[bin] = red4[0] + red4[1] + red4[2] + red4[3];
        __syncthreads();
    }
    grid.sync();
    // ===== phase 2b: exclusive scan of binsum (block 0, 512 slots) =====
    if (b == 0) {
        int i0 = 2 * t, i1 = 2 * t + 1;
        int a0 = (i0 < nb) ? binsum[i0] : 0;
        int a1 = (i1 < nb) ? binsum[i1] : 0;
        int s = a0 + a1;
        ts[t] = s;
        __syncthreads();
        for (int off = 1; off < 256; off <<= 1) {
            int v = (t >= off) ? ts[t - off] : 0;
            __syncthreads();
            ts[t] += v;
            __syncthreads();
        }
        int excl = ts[t] - s;
        if (i0 < nb) binsum[i0] = excl;
        if (i1 < nb) binsum[i1] = excl + a0;
    }
    grid.sync();
    // ===== phase 2c: per-bin exclusive scan of g entries + bin offset =====
    for (int bin = b; bin < nb; bin += g) {
        int c = (g + 255) >> 8;
        int lo = t * c, hi = min(g, lo + c);
        int s = 0;
        for (int i = lo; i < hi; i++) s += gh[(long)bin * g + i];
        ts[t] = s;
        __syncthreads();
        for (int off = 1; off < 256; off <<= 1) {
            int v = (t >= off) ? ts[t - off] : 0;
            __syncthreads();
            ts[t] += v;
            __syncthreads();
        }
        int run = ts[t] - s + binsum[bin];
        for (int i = lo; i < hi; i++) {
            int v = gh[(long)bin * g + i];
            gh[(long)bin * g + i] = run;
            run += v;
        }
        __syncthreads();
    }
    grid.sync();
    // ===== phase 3: bucket scatter (LDS cursors, race-free) + gemm1 MFMA =====
    {
        for (int i = t; i < nb; i += 256) lds[i] = gh[(long)i * g + b];
        __syncthreads();
        int lo = b * epb, hi = min(e, lo + epb);
        for (int i = lo + t; i < hi; i += 256) {
            int d = edst[i], s2 = esrc[i];
            int pos = atomicAdd(&lds[d >> 7], 1);  // LDS atomic: per-CU, cheap
            sorted[pos] = (((long long)d) << 32) | (unsigned int)s2;
        }
        // gemm1: h = bf16(x) @ bf16(W_conv), 16-row wave tiles, LDS-free
        int mrow = lane & 15, quad = lane >> 4;
        int ntile = (n + 15) >> 4;
        for (int tile = wg; tile < ntile; tile += nw) {
            int rw = tile * 16;
            int r = rw + mrow;
            if (r >= n) r = n - 1;  // clamp; stores guarded
            f32x4 acc[8];
#pragma unroll
            for (int nt = 0; nt < 8; nt++) acc[nt] = (f32x4){0.f, 0.f, 0.f, 0.f};
#pragma unroll
            for (int ks = 0; ks < 4; ks++) {
                const float* px = &x[(long)r * C_DIM + ks * 32 + quad * 8];
                float4 xa = *(const float4*)px;
                float4 xb = *(const float4*)(px + 4);
                uint4 au;
                au.x = pack_bf16(xa.x, xa.y);
                au.y = pack_bf16(xa.z, xa.w);
                au.z = pack_bf16(xb.x, xb.y);
                au.w = pack_bf16(xb.z, xb.w);
                union { uint4 u; short8 s; } cv;
                cv.u = au;
                short8 A = cv.s;
#pragma unroll
                for (int nt = 0; nt < 8; nt++) {
                    short8 B = *(const short8*)&WcT[(nt * 16 + mrow) * 128 + ks * 32 + quad * 8];
                    acc[nt] = __builtin_amdgcn_mfma_f32_16x16x32_bf16(A, B, acc[nt], 0, 0, 0);
                }
            }
            bool evenc = (mrow & 1) == 0;
#pragma unroll
            for (int nt = 0; nt < 8; nt++)
#pragma unroll
                for (int reg = 0; reg < 4; reg++) {
                    float v = acc[nt][reg];
                    float pv = __shfl_xor(v, 1);
                    int rr = rw + quad * 4 + reg;
                    if (evenc && rr < n)
                        hb[(long)rr * 64 + ((nt * 16 + mrow) >> 1)] = pack_bf16(v, pv);
                }
        }
    }
    grid.sync();
    // ===== phase 4: per-bucket in-LDS counting sort -> compact CSR + dinv =====
    for (int bk = b; bk < nb; bk += g) {
        int node0 = bk << 7;
        int nloc = min(128, n - node0);
        int start = gh[(long)bk * g];
        int end = (bk + 1 < nb) ? gh[(long)(bk + 1) * g] : e;
        if (t < 128) ch[t] = 0;
        __syncthreads();
        for (int i = start + t; i < end; i += 256)
            atomicAdd(&ch[(int)(sorted[i] >> 32) & 127], 1);
        __syncthreads();
        if (t < 128) cbase[t] = ch[t];
        __syncthreads();
        for (int off = 1; off < 128; off <<= 1) {
            int v = 0;
            if (t < 128 && t >= off) v = cbase[t - off];
            __syncthreads();
            if (t < 128) cbase[t] += v;
            __syncthreads();
        }
        int excl = (t < 128) ? (cbase[t] - ch[t]) : 0;
        if (t < nloc) {
            rowptr[node0 + t] = start + excl;
            dinv[node0 + t] = rsqrtf((float)ch[t] + 1.0f);  // +1 self-loop
        }
        if (bk == nb - 1 && t == 0) rowptr[n] = e;
        if (t < 128) ccur[t] = excl;
        __syncthreads();
        for (int i = start + t; i < end; i += 256) {
            long long pk = sorted[i];
            int dl = (int)(pk >> 32) & 127;
            int pos = atomicAdd(&ccur[dl], 1);
            bsrc[start + pos] = (int)(pk & 0xffffffffLL);
        }
        __syncthreads();
    }
    grid.sync();
    // ===== phase 5: fused aggregate + bias + relu*x + LN + residual =====
    {
        int sub = lane & 15, grp = lane >> 4;
        // lane-dependent epilogue constants hoisted out of the node loop
        float4 bca = *(const float4*)&bconv[sub * 8];
        float4 bcb = *(const float4*)&bconv[sub * 8 + 4];
        float4 ga = *(const float4*)&gamma[sub * 8];
        float4 gb = *(const float4*)&gamma[sub * 8 + 4];
        float4 ba = *(const float4*)&beta[sub * 8];
        float4 bb = *(const float4*)&beta[sub * 8 + 4];
        float bcv[8] = {bca.x, bca.y, bca.z, bca.w, bcb.x, bcb.y, bcb.z, bcb.w};
        float gv[8] = {ga.x, ga.y, ga.z, ga.w, gb.x, gb.y, gb.z, gb.w};
        float bev[8] = {ba.x, ba.y, ba.z, ba.w, bb.x, bb.y, bb.z, bb.w};
        for (int i = wg; i < n; i += nw) {
            float di = dinv[i];
            int beg = rowptr[i], end = rowptr[i + 1];
            uint4 us = *(const uint4*)(hb + (long)i * 64 + sub * 4);
            float wself = (grp == 0) ? di * di : 0.f;
            float acc[8];
            acc[0] = wself * blo(us.x); acc[1] = wself * bhi(us.x);
            acc[2] = wself * blo(us.y); acc[3] = wself * bhi(us.y);
            acc[4] = wself * blo(us.z); acc[5] = wself * bhi(us.z);
            acc[6] = wself * blo(us.w); acc[7] = wself * bhi(us.w);
            int k = beg + grp;
            for (; k + 4 < end; k += 8) {  // 8 edges in flight per wave iter
                int s0 = bsrc[k];
                int s1 = bsrc[k + 4];
                float w0 = dinv[s0] * di;
                float w1 = dinv[s1] * di;
                uint4 u0 = *(const uint4*)(hb + (long)s0 * 64 + sub * 4);
                uint4 u1 = *(const uint4*)(hb + (long)s1 * 64 + sub * 4);
                acc[0] += w0 * blo(u0.x); acc[1] += w0 * bhi(u0.x);
                acc[2] += w0 * blo(u0.y); acc[3] += w0 * bhi(u0.y);
                acc[4] += w0 * blo(u0.z); acc[5] += w0 * bhi(u0.z);
                acc[6] += w0 * blo(u0.w); acc[7] += w0 * bhi(u0.w);
                acc[0] += w1 * blo(u1.x); acc[1] += w1 * bhi(u1.x);
                acc[2] += w1 * blo(u1.y); acc[3] += w1 * bhi(u1.y);
                acc[4] += w1 * blo(u1.z); acc[5] += w1 * bhi(u1.z);
                acc[6] += w1 * blo(u1.w); acc[7] += w1 * bhi(u1.w);
            }
            for (; k < end; k += 4) {
                int s = bsrc[k];
                float wv = dinv[s] * di;
                uint4 u = *(const uint4*)(hb + (long)s * 64 + sub * 4);
                acc[0] += wv * blo(u.x); acc[1] += wv * bhi(u.x);
                acc[2] += wv * blo(u.y); acc[3] += wv * bhi(u.y);
                acc[4] += wv * blo(u.z); acc[5] += wv * bhi(u.z);
                acc[6] += wv * blo(u.w); acc[7] += wv * bhi(u.w);
            }
#pragma unroll
            for (int j = 0; j < 8; j++) {
                acc[j] += __shfl_xor(acc[j], 16);
                acc[j] += __shfl_xor(acc[j], 32);
            }
            float4 xa = *(const float4*)&x[(long)i * C_DIM + sub * 8];
            float4 xb = *(const float4*)&x[(long)i * C_DIM + sub * 8 + 4];
            float xv[8] = {xa.x, xa.y, xa.z, xa.w, xb.x, xb.y, xb.z, xb.w};
            float a[8];
#pragma unroll
            for (int j = 0; j < 8; j++) a[j] = fmaxf(acc[j] + bcv[j], 0.f) * xv[j];
            float s = a[0] + a[1] + a[2] + a[3] + a[4] + a[5] + a[6] + a[7];
#pragma unroll
            for (int off = 1; off < 16; off <<= 1) s += __shfl_xor(s, off);
            float mu = s * (1.0f / 128.0f);
            float d[8], v = 0.f;
#pragma unroll
            for (int j = 0; j < 8; j++) { d[j] = a[j] - mu; v += d[j] * d[j]; }
#pragma unroll
            for (int off = 1; off < 16; off <<= 1) v += __shfl_xor(v, off);
            float inv = rsqrtf(v * (1.0f / 128.0f) + EPS);
            if (grp == 0) {
                float o[8];
#pragma unroll
                for (int j = 0; j < 8; j++) o[j] = d[j] * inv * gv[j] + bev[j] + xv[j];
                uint4 p;
                p.x = pack_bf16(o[0], o[1]);
                p.y = pack_bf16(o[2], o[3]);
                p.z = pack_bf16(o[4], o[5]);
                p.w = pack_bf16(o[6], o[7]);
                *(uint4*)(zb + (long)i * 64 + sub * 4) = p;
            }
        }
    }
    grid.sync();
    // ===== phase 6: gemm2 = z @ W_fc + b_fc via bf16 MFMA =====
    {
        const unsigned short* zs = (const unsigned short*)zb;
        int mrow = lane & 15, quad = lane >> 4;
        int ntile = (n + 63) >> 6;
        for (int tile = wg; tile < ntile; tile += nw) {
            int r0 = tile * 64;
            f32x4 acc[4][3];
#pragma unroll
            for (int m = 0; m < 4; m++)
#pragma unroll
                for (int nt = 0; nt < 3; nt++) acc[m][nt] = (f32x4){0.f, 0.f, 0.f, 0.f};
#pragma unroll
            for (int ks = 0; ks < 4; ks++) {
                short8 A[4], B[3];
#pragma unroll
                for (int m = 0; m < 4; m++) {
                    int r = r0 + m * 16 + mrow;
                    if (r >= n) r = n - 1;  // clamp (stores guarded)
                    A[m] = *(const short8*)&zs[(long)r * 128 + ks * 32 + quad * 8];
                }
#pragma unroll
                for (int nt = 0; nt < 3; nt++)
                    B[nt] = *(const short8*)&WT[(nt * 16 + mrow) * 128 + ks * 32 + quad * 8];
#pragma unroll
                for (int m = 0; m < 4; m++)
#pragma unroll
                    for (int nt = 0; nt < 3; nt++)
                        acc[m][nt] = __builtin_amdgcn_mfma_f32_16x16x32_bf16(A[m], B[nt], acc[m][nt], 0, 0, 0);
            }
#pragma unroll
            for (int nt = 0; nt < 3; nt++) {
                int c = nt * 16 + mrow;
                if (c < 40) {
                    float bias = bfc[c];
#pragma unroll
                    for (int m = 0; m < 4; m++) {
#pragma unroll
                        for (int reg = 0; reg < 4; reg++) {
                            int r = r0 + m * 16 + quad * 4 + reg;
                            if (r < n) out[(long)r * 40 + c] = acc[m][nt][reg] + bias;
                        }
                    }
                }
            }
        }
    }
}

extern "C" void kernel_launch(void* const* d_in, const int* in_sizes, int n_in,
                              void* d_out, int out_size, void* d_ws, size_t ws_size,
                              hipStream_t stream) {
    const float* x     = (const float*)d_in[0];
    const int*   ei    = (const int*)d_in[1];
    const float* Wc    = (const float*)d_in[2];
    const float* bc    = (const float*)d_in[3];
    const float* gamma = (const float*)d_in[4];
    const float* beta  = (const float*)d_in[5];
    const float* Wfc   = (const float*)d_in[6];
    const float* bfc   = (const float*)d_in[7];
    float* out = (float*)d_out;

    int N = in_sizes[0] / C_DIM;
    int E = in_sizes[1] / 2;
    const int* esrc = ei;
    const int* edst = ei + E;
    int nb = (N + 127) >> 7;

    char* p = (char*)d_ws;
    auto carve = [&](size_t bytes) {
        void* q = (void*)p;
        p += (bytes + 255) & ~(size_t)255;
        return q;
    };
    unsigned* hb        = (unsigned*)carve((size_t)N * 64 * 4);
    unsigned* zb        = (unsigned*)carve((size_t)N * 64 * 4);
    unsigned short* WcT = (unsigned short*)carve(128 * 128 * 2);
    unsigned short* WT  = (unsigned short*)carve(48 * 128 * 2);
    float* dinv         = (float*)carve((size_t)N * 4);
    int*   gh           = (int*)carve((size_t)nb * 1024 * 4);
    int*   binsum       = (int*)carve((size_t)MAXNB * 4);
    long long* sorted   = (long long*)carve((size_t)E * 8);
    int*   bsrc         = (int*)carve((size_t)E * 4);
    int*   rowptr       = (int*)carve((size_t)(N + 1) * 4);

    // co-residency: launch_bounds(256,4) guarantees 4 blocks/CU; query anyway
    int nblk = 0;
    (void)hipOccupancyMaxActiveBlocksPerMultiprocessor(&nblk, mega, 256, 0);
    if (nblk < 1) nblk = 1;
    int g = nblk * 256;
    if (g > 1024) g = 1024;

    void* args[] = {
        (void*)&x, (void*)&esrc, (void*)&edst, (void*)&Wc, (void*)&bc,
        (void*)&gamma, (void*)&beta, (void*)&Wfc, (void*)&bfc,
        (void*)&hb, (void*)&zb, (void*)&WcT, (void*)&WT,
        (void*)&dinv, (void*)&gh, (void*)&binsum, (void*)&sorted,
        (void*)&bsrc, (void*)&rowptr, (void*)&out,
        (void*)&N, (void*)&E, (void*)&nb,
    };
    (void)hipLaunchCooperativeKernel((const void*)mega, dim3(g), dim3(256), args, 0, stream);
}